// Round 2
// baseline (85.738 us; speedup 1.0000x reference)
//
#include <hip/hip_runtime.h>
#include <hip/hip_bf16.h>

// smartorn layer: out[b,j] = elu(power[j] * sum_i x[b,i]*gate(i,j) - bias[j])
// gate(i,j) = strength(dpb . outdir_i) * strength(dpb . indir_j)
//   dp = pos_j - pos_i, dpb = dp / sqrt(max(|dp|^2, 1e-5))
//   strength(v) = (exp(v) - e^-1) / (e - e^-1)
// ALL tensors are float32 per the reference (prior round's NaN = f32 data
// misread as bf16). Never materialize the N x N gate: recompute per-pair,
// accumulate B=8 batches in registers. Deterministic i-split via ws scratch.

#define NN 4096
#define NB 8
#define JT 64        // j per block (one wave of j per 64 lanes)
#define CHUNK 256    // i staged per LDS pass

__global__ __launch_bounds__(256) void smartorn_phase1(
    const float* __restrict__ x,       // (B, N)
    const float* __restrict__ pos,     // (N, 3)
    const float* __restrict__ indir,   // (N, 3)
    const float* __restrict__ outdir,  // (N, 3)
    const float* __restrict__ power,   // (N)   (used only when fused)
    const float* __restrict__ bias,    // (N)
    float* __restrict__ ws,            // (isplit, B, N) partials
    float* __restrict__ out,           // (B, N) (used only when fused)
    int isplit, int fused)
{
    // packed for ds_read_b128 (inner-loop LDS index is wave-uniform -> broadcast)
    __shared__ float4 sg[CHUNK][2];    // {px,py,pz,ox} {oy,oz,-,-}
    __shared__ float4 sxv[CHUNK][2];   // x[b0..3], x[b4..7]
    __shared__ float  sacc[4][JT][NB];

    const int jt  = blockIdx.x / isplit;
    const int is  = blockIdx.x % isplit;
    const int ipb = NN / isplit;
    const int tid = threadIdx.x;
    const int tj  = tid & 63;   // j lane
    const int sub = tid >> 6;   // i-subrange 0..3 (wave-uniform)

    const int j = jt * JT + tj;
    const float pjx = pos[j * 3 + 0];
    const float pjy = pos[j * 3 + 1];
    const float pjz = pos[j * 3 + 2];
    const float inx = indir[j * 3 + 0];
    const float iny = indir[j * 3 + 1];
    const float inz = indir[j * 3 + 2];

    float acc[NB];
#pragma unroll
    for (int b = 0; b < NB; ++b) acc[b] = 0.f;

    const float C1 = 0.36787944117144233f;  // e^-1
    const float SC = 0.18101541533756566f;  // 1 / (e - e^-1)^2

    for (int ibase = is * ipb; ibase < is * ipb + ipb; ibase += CHUNK) {
        __syncthreads();   // protect LDS from previous chunk's readers
        {
            const int gi = ibase + tid;
            sg[tid][0] = make_float4(pos[gi * 3 + 0], pos[gi * 3 + 1],
                                     pos[gi * 3 + 2], outdir[gi * 3 + 0]);
            sg[tid][1] = make_float4(outdir[gi * 3 + 1], outdir[gi * 3 + 2], 0.f, 0.f);
            sxv[tid][0] = make_float4(x[0 * NN + gi], x[1 * NN + gi],
                                      x[2 * NN + gi], x[3 * NN + gi]);
            sxv[tid][1] = make_float4(x[4 * NN + gi], x[5 * NN + gi],
                                      x[6 * NN + gi], x[7 * NN + gi]);
        }
        __syncthreads();

        const int i0 = sub * (CHUNK / 4);
#pragma unroll 4
        for (int il = i0; il < i0 + CHUNK / 4; ++il) {
            const float4 g0 = sg[il][0];
            const float4 g1 = sg[il][1];
            const float dx = pjx - g0.x;
            const float dy = pjy - g0.y;
            const float dz = pjz - g0.z;
            float n2 = fmaf(dx, dx, fmaf(dy, dy, dz * dz));
            n2 = fmaxf(n2, 1e-5f);
            const float inv = rsqrtf(n2);
            const float da = fmaf(dx, g0.w, fmaf(dy, g1.x, dz * g1.y)) * inv;
            const float db = fmaf(dx, inx, fmaf(dy, iny, dz * inz)) * inv;
            const float g = (__expf(da) - C1) * (__expf(db) - C1) * SC;
            const float4 xa = sxv[il][0];
            const float4 xb = sxv[il][1];
            acc[0] = fmaf(xa.x, g, acc[0]);
            acc[1] = fmaf(xa.y, g, acc[1]);
            acc[2] = fmaf(xa.z, g, acc[2]);
            acc[3] = fmaf(xa.w, g, acc[3]);
            acc[4] = fmaf(xb.x, g, acc[4]);
            acc[5] = fmaf(xb.y, g, acc[5]);
            acc[6] = fmaf(xb.z, g, acc[6]);
            acc[7] = fmaf(xb.w, g, acc[7]);
        }
    }

#pragma unroll
    for (int b = 0; b < NB; ++b) sacc[sub][tj][b] = acc[b];
    __syncthreads();

    for (int p = tid; p < JT * NB; p += 256) {
        const int bb = p >> 6;
        const int jj = p & 63;
        const float s = sacc[0][jj][bb] + sacc[1][jj][bb] +
                        sacc[2][jj][bb] + sacc[3][jj][bb];
        const int jg = jt * JT + jj;
        if (!fused) {
            ws[(is * NB + bb) * NN + jg] = s;
        } else {
            const float v = fmaf(s, power[jg], -bias[jg]);
            out[bb * NN + jg] = v > 0.f ? v : expm1f(v);
        }
    }
}

__global__ __launch_bounds__(256) void smartorn_phase2(
    const float* __restrict__ ws,      // (isplit, B, N)
    const float* __restrict__ power,   // (N)
    const float* __restrict__ bias,    // (N)
    float* __restrict__ out,           // (B, N)
    int isplit)
{
    const int t = blockIdx.x * 256 + threadIdx.x;   // 0 .. B*N-1
    const int j = t & (NN - 1);
    const int b = t >> 12;
    float s = 0.f;
    for (int is = 0; is < isplit; ++is)
        s += ws[(is * NB + b) * NN + j];
    const float v = fmaf(s, power[j], -bias[j]);
    out[t] = v > 0.f ? v : expm1f(v);
}

extern "C" void kernel_launch(void* const* d_in, const int* in_sizes, int n_in,
                              void* d_out, int out_size, void* d_ws, size_t ws_size,
                              hipStream_t stream) {
    const float* x      = (const float*)d_in[0];
    const float* pos    = (const float*)d_in[1];
    const float* indir  = (const float*)d_in[2];
    const float* outdir = (const float*)d_in[3];
    const float* power  = (const float*)d_in[4];
    const float* bias   = (const float*)d_in[5];
    float* ws  = (float*)d_ws;
    float* out = (float*)d_out;

    const size_t slab = (size_t)NB * NN * sizeof(float);   // 128 KiB per i-split
    int isplit = 1;
    while (isplit < 16 && (size_t)(isplit * 2) * slab <= ws_size) isplit *= 2;
    const int fused = (slab > ws_size) ? 1 : 0;   // no scratch at all -> single phase
    if (fused) isplit = 1;

    dim3 block(256);
    dim3 grid1((NN / JT) * isplit);
    hipLaunchKernelGGL(smartorn_phase1, grid1, block, 0, stream,
                       x, pos, indir, outdir, power, bias, ws, out, isplit, fused);

    if (!fused) {
        dim3 grid2((NB * NN) / 256);
        hipLaunchKernelGGL(smartorn_phase2, grid2, block, 0, stream,
                           ws, power, bias, out, isplit);
    }
}

// Round 3
// 83.223 us; speedup vs baseline: 1.0302x; 1.0302x over previous
//
#include <hip/hip_runtime.h>

// smartorn layer: out[b,j] = elu(power[j] * sum_i x[b,i]*gate(i,j) - bias[j])
// gate(i,j) = strength(dpb . outdir_i) * strength(dpb . indir_j)
//   dp = pos_j - pos_i, dpb = dp / sqrt(max(|dp|^2, 1e-5))
//   strength(v) = (exp(v) - e^-1) / (e - e^-1)
//
// All tensors float32. The inner-loop i-index is wave-uniform, so all per-i
// operands (pos_i, outdir_i, x[*,i]) are scalar: pack them 64 B/record and
// read via uniform s_load_dwordx4 (readfirstlane forces uniformity) — no LDS
// staging, no inner barriers. j lives per-lane; B=8 accumulators in VGPRs
// (float2 pairs -> v_pk_fma_f32).

#define NN 4096
#define NB 8
#define JT 64               // j per block (one wave of 64 j-lanes)
#define ISPLIT 16           // i-splits per j-tile (deterministic, via ws)
#define IPB (NN / ISPLIT)   // 256 i per block
#define IPW (IPB / 4)       // 64 i per wave
#define PACK_FLOATS (NN * 16)   // packed per-i records: 16 f32 each

typedef __attribute__((ext_vector_type(2))) float f2;

__global__ __launch_bounds__(256) void smartorn_pack(
    const float* __restrict__ x,       // (B, N)
    const float* __restrict__ pos,     // (N, 3)
    const float* __restrict__ outdir,  // (N, 3)
    float* __restrict__ pack)          // (N, 16)
{
    const int i = blockIdx.x * 256 + threadIdx.x;
    if (i >= NN) return;
    float4* p = (float4*)(pack + (size_t)i * 16);
    p[0] = make_float4(pos[i * 3 + 0], pos[i * 3 + 1], pos[i * 3 + 2],
                       outdir[i * 3 + 0]);
    p[1] = make_float4(outdir[i * 3 + 1], outdir[i * 3 + 2],
                       x[0 * NN + i], x[1 * NN + i]);
    p[2] = make_float4(x[2 * NN + i], x[3 * NN + i],
                       x[4 * NN + i], x[5 * NN + i]);
    p[3] = make_float4(x[6 * NN + i], x[7 * NN + i], 0.f, 0.f);
}

__global__ __launch_bounds__(256) void smartorn_phase1(
    const float* __restrict__ pack,    // (N, 16)
    const float* __restrict__ pos,     // (N, 3)
    const float* __restrict__ indir,   // (N, 3)
    float* __restrict__ part)          // (ISPLIT, B, N)
{
    __shared__ float sacc[4][JT][NB];

    const int jt  = blockIdx.x / ISPLIT;
    const int is  = blockIdx.x % ISPLIT;
    const int tid = threadIdx.x;
    const int tj  = tid & 63;
    const int sub = __builtin_amdgcn_readfirstlane(tid >> 6);  // wave-uniform

    const int j = jt * JT + tj;
    const float pjx = pos[j * 3 + 0];
    const float pjy = pos[j * 3 + 1];
    const float pjz = pos[j * 3 + 2];
    const float inx = indir[j * 3 + 0];
    const float iny = indir[j * 3 + 1];
    const float inz = indir[j * 3 + 2];

    f2 a01 = {0.f, 0.f}, a23 = {0.f, 0.f}, a45 = {0.f, 0.f}, a67 = {0.f, 0.f};

    const float C1 = 0.36787944117144233f;  // e^-1
    const float SC = 0.18101541533756566f;  // 1 / (e - e^-1)^2

    // uniform base -> every pk[] access below is a scalar (s_load) access
    const float4* pk = (const float4*)pack + (size_t)(is * IPB + sub * IPW) * 4;

#pragma unroll 2
    for (int il = 0; il < IPW; ++il) {
        const float4 q0 = pk[il * 4 + 0];   // {px, py, pz, ox}
        const float4 q1 = pk[il * 4 + 1];   // {oy, oz, x0, x1}
        const float4 q2 = pk[il * 4 + 2];   // {x2, x3, x4, x5}
        const float4 q3 = pk[il * 4 + 3];   // {x6, x7, -, -}

        const float dx = pjx - q0.x;
        const float dy = pjy - q0.y;
        const float dz = pjz - q0.z;
        float n2 = fmaf(dx, dx, fmaf(dy, dy, dz * dz));
        n2 = fmaxf(n2, 1e-5f);
        const float inv = rsqrtf(n2);
        const float da = fmaf(dx, q0.w, fmaf(dy, q1.x, dz * q1.y)) * inv;
        const float db = fmaf(dx, inx, fmaf(dy, iny, dz * inz)) * inv;
        const float g = (__expf(da) - C1) * (__expf(db) - C1) * SC;

        const f2 gv = {g, g};
        a01 = __builtin_elementwise_fma((f2){q1.z, q1.w}, gv, a01);
        a23 = __builtin_elementwise_fma((f2){q2.x, q2.y}, gv, a23);
        a45 = __builtin_elementwise_fma((f2){q2.z, q2.w}, gv, a45);
        a67 = __builtin_elementwise_fma((f2){q3.x, q3.y}, gv, a67);
    }

    sacc[sub][tj][0] = a01.x;  sacc[sub][tj][1] = a01.y;
    sacc[sub][tj][2] = a23.x;  sacc[sub][tj][3] = a23.y;
    sacc[sub][tj][4] = a45.x;  sacc[sub][tj][5] = a45.y;
    sacc[sub][tj][6] = a67.x;  sacc[sub][tj][7] = a67.y;
    __syncthreads();

    for (int p = tid; p < JT * NB; p += 256) {
        const int bb = p >> 6;
        const int jj = p & 63;
        const float s = sacc[0][jj][bb] + sacc[1][jj][bb] +
                        sacc[2][jj][bb] + sacc[3][jj][bb];
        part[(is * NB + bb) * NN + jt * JT + jj] = s;
    }
}

__global__ __launch_bounds__(256) void smartorn_phase2(
    const float* __restrict__ part,    // (ISPLIT, B, N)
    const float* __restrict__ power,   // (N)
    const float* __restrict__ bias,    // (N)
    float* __restrict__ out)           // (B, N)
{
    const int t = blockIdx.x * 256 + threadIdx.x;   // 0 .. B*N-1
    const int j = t & (NN - 1);
    const int b = t >> 12;
    float s = 0.f;
#pragma unroll
    for (int is = 0; is < ISPLIT; ++is)
        s += part[(is * NB + b) * NN + j];
    const float v = fmaf(s, power[j], -bias[j]);
    out[t] = v > 0.f ? v : expm1f(v);
}

extern "C" void kernel_launch(void* const* d_in, const int* in_sizes, int n_in,
                              void* d_out, int out_size, void* d_ws, size_t ws_size,
                              hipStream_t stream) {
    const float* x      = (const float*)d_in[0];
    const float* pos    = (const float*)d_in[1];
    const float* indir  = (const float*)d_in[2];
    const float* outdir = (const float*)d_in[3];
    const float* power  = (const float*)d_in[4];
    const float* bias   = (const float*)d_in[5];
    float* ws   = (float*)d_ws;
    float* pack = ws;                       // 256 KiB
    float* part = ws + PACK_FLOATS;         // 2 MiB
    float* out  = (float*)d_out;

    dim3 block(256);
    hipLaunchKernelGGL(smartorn_pack, dim3(NN / 256), block, 0, stream,
                       x, pos, outdir, pack);
    hipLaunchKernelGGL(smartorn_phase1, dim3((NN / JT) * ISPLIT), block, 0, stream,
                       pack, pos, indir, part);
    hipLaunchKernelGGL(smartorn_phase2, dim3((NB * NN) / 256), block, 0, stream,
                       part, power, bias, out);
}